// Round 2
// baseline (14567.883 us; speedup 1.0000x reference)
//
#include <hip/hip_runtime.h>
#include <math.h>

#define L 50
#define ML 64
#define VOCAB 32000
#define EMBED 1024
#define HID 1024
#define HH 512
#define TOT (VOCAB+ML)

// workspace layout (float offsets)
#define WS_ENC_GATES 0        // [2][4096]
#define WS_ENC_OUTS  10240    // [64][1024]
#define WS_COPY_ENC  75776    // [64][1024]
#define WS_H_DEC     141312   // [2][1024]
#define WS_C_DEC     143360   // [2][1024]
#define WS_X_DEC     145408   // [3072]
#define WS_DGATES    148480   // [4096]
#define WS_LOGITS    152576   // [32064]
#define WS_PARTS     184640   // [512*4] {lmax,sumexp,bestkey,bestidx}
#define WS_BAR       186688   // 256 ints: enc slots 0..50, dec bar 51+t, tickets 128+t

__device__ __forceinline__ float wred_sum(float v){
  #pragma unroll
  for(int o=32;o;o>>=1) v += __shfl_xor(v,o,64);
  return v;
}
__device__ __forceinline__ float wred_max(float v){
  #pragma unroll
  for(int o=32;o;o>>=1) v = fmaxf(v,__shfl_xor(v,o,64));
  return v;
}
__device__ __forceinline__ float sigm(float x){ return 1.0f/(1.0f+__expf(-x)); }
__device__ __forceinline__ float d4(float4 a, float4 b){ return a.x*b.x + a.y*b.y + a.z*b.z + a.w*b.w; }

// grid barrier: all nblk blocks must call with same slot; slot zero-initialized per launch
__device__ __forceinline__ void gridbar(int* bar, int slot, int nblk){
  __syncthreads();
  if(threadIdx.x==0){
    __threadfence();
    __hip_atomic_fetch_add(&bar[slot], 1, __ATOMIC_RELEASE, __HIP_MEMORY_SCOPE_AGENT);
    while(__hip_atomic_load(&bar[slot], __ATOMIC_ACQUIRE, __HIP_MEMORY_SCOPE_AGENT) < nblk)
      __builtin_amdgcn_s_sleep(2);
  }
  __syncthreads();
}

// ================= encoder: persistent, weights in registers, 51 grid barriers =================
__global__ __launch_bounds__(256,2) void k_encoder(
  const int* __restrict__ xt, const float* __restrict__ emb,
  const float* __restrict__ Wih_f, const float* __restrict__ Whh_f,
  const float* __restrict__ bih_f, const float* __restrict__ bhh_f,
  const float* __restrict__ Wih_b, const float* __restrict__ Whh_b,
  const float* __restrict__ bih_b, const float* __restrict__ bhh_b,
  const float* __restrict__ copy_W, const float* __restrict__ copy_b,
  float* __restrict__ ws, float* __restrict__ out, int* __restrict__ bar)
{
  __shared__ __align__(16) float xe[1024];
  __shared__ __align__(16) float hc[1024];
  __shared__ __align__(16) float cc[1024];
  const int tid=threadIdx.x, b=blockIdx.x, wave=tid>>6, lane=tid&63;
  float* gates   = ws + WS_ENC_GATES;
  float* enc_outs= ws + WS_ENC_OUTS;
  float* cenc    = ws + WS_COPY_ENC;
  float* h_dec   = ws + WS_H_DEC;
  float* c_dec   = ws + WS_C_DEC;
  float* x_dec   = ws + WS_X_DEC;

  // load this wave's 2 weight rows into registers (persist across all 50 steps)
  float4 wih[2][4], whh[2][2]; float bias[2];
  #pragma unroll
  for(int rr=0;rr<2;rr++){
    int r=b*8+wave*2+rr; bool isF=(r<2048); int rl=isF?r:(r-2048);
    const float* wp=(isF?Wih_f:Wih_b)+(size_t)rl*EMBED;
    #pragma unroll
    for(int c4=0;c4<4;c4++) wih[rr][c4]=*(const float4*)(wp+c4*256+lane*4);
    const float* hp=(isF?Whh_f:Whh_b)+(size_t)rl*HH;
    #pragma unroll
    for(int c2=0;c2<2;c2++) whh[rr][c2]=*(const float4*)(hp+c2*256+lane*4);
    bias[rr]= isF?(bih_f[rl]+bhh_f[rl]):(bih_b[rl]+bhh_b[rl]);
  }
  for(int j=tid;j<1024;j+=256){ hc[j]=0.0f; cc[j]=0.0f; }
  __syncthreads();

  for(int t=0;t<L;t++){
    const int tok=xt[t];
    const float* er=emb+(size_t)tok*EMBED;
    for(int j=tid;j<1024;j+=256) xe[j]=er[j];
    if(t>0){
      const float* gp=gates+((t-1)&1)*4096;
      for(int u=tid;u<1024;u+=256){
        int base=(u<512)?0:2048, uu=(u<512)?u:(u-512);
        float ig=gp[base+uu], fg=gp[base+512+uu], gg=gp[base+1024+uu], og=gp[base+1536+uu];
        float c=sigm(fg)*cc[u]+sigm(ig)*tanhf(gg);
        float h=sigm(og)*tanhf(c);
        cc[u]=c; hc[u]=h;
        if(b==0) enc_outs[(size_t)(t-1)*1024+u]=h;
      }
    }
    __syncthreads();
    float* gw=gates+(t&1)*4096;
    #pragma unroll
    for(int rr=0;rr<2;rr++){
      int r=b*8+wave*2+rr; bool isF=(r<2048);
      const float* hs=&hc[isF?0:512];
      float acc=0.0f;
      #pragma unroll
      for(int c4=0;c4<4;c4++) acc+=d4(wih[rr][c4], *(const float4*)(&xe[c4*256+lane*4]));
      #pragma unroll
      for(int c2=0;c2<2;c2++) acc+=d4(whh[rr][c2], *(const float4*)(&hs[c2*256+lane*4]));
      acc=wred_sum(acc);
      if(lane==0) gw[r]=acc+bias[rr];
    }
    gridbar(bar, t, (int)gridDim.x);
  }

  // final cell update (t=49), state handoff, pad-zero, x_dec init
  {
    const float* gp=gates+((L-1)&1)*4096;
    for(int u=tid;u<1024;u+=256){
      int base=(u<512)?0:2048, uu=(u<512)?u:(u-512);
      float ig=gp[base+uu], fg=gp[base+512+uu], gg=gp[base+1024+uu], og=gp[base+1536+uu];
      float c=sigm(fg)*cc[u]+sigm(ig)*tanhf(gg);
      float h=sigm(og)*tanhf(c);
      if(b==0){
        enc_outs[(size_t)(L-1)*1024+u]=h;
        h_dec[1024+u]=h;   // h0 in parity-1 buffer
        c_dec[1024+u]=c;   // c0 in parity-1 buffer
        out[u]=h;          // states[0]
      }
    }
    if(b==1) for(int j=tid;j<(ML-L)*1024;j+=256) enc_outs[(size_t)L*1024+j]=0.0f;
    if(b==2) for(int j=tid;j<1024;j+=256){
      x_dec[j]=emb[j];         // sos = embedding[0]
      x_dec[1024+j]=0.0f;      // selective (first step)
      x_dec[2048+j]=0.0f;      // attentive (first step)
    }
  }
  gridbar(bar, L, (int)gridDim.x);

  // copy_enc = tanh(enc_outs @ copy_W^T + copy_b): blocks 0..255, 1 row per wave
  if(b<256){
    int j=b*4+wave;
    const float* wr=copy_W+(size_t)j*1024;
    float4 w0=*(const float4*)(wr      +lane*4);
    float4 w1=*(const float4*)(wr+256  +lane*4);
    float4 w2=*(const float4*)(wr+512  +lane*4);
    float4 w3=*(const float4*)(wr+768  +lane*4);
    float bj=copy_b[j];
    for(int k=0;k<ML;k++){
      const float* er2=enc_outs+(size_t)k*1024;
      float acc = d4(w0,*(const float4*)(er2      +lane*4))
                + d4(w1,*(const float4*)(er2+256  +lane*4))
                + d4(w2,*(const float4*)(er2+512  +lane*4))
                + d4(w3,*(const float4*)(er2+768  +lane*4));
      acc=wred_sum(acc);
      if(lane==0) cenc[(size_t)k*1024+j]=tanhf(acc+bj);
    }
  }
}

// ================= decoder: one kernel per step =================
// P1: gates GEMV -> gridbar -> P2: cell + gen/copy GEMV + softmax partials -> ticket tail:
// finalize softmax/argmax of this step, write probs/actions, prep next step's x_dec.
__global__ __launch_bounds__(256,2) void k_dec_step(
  const int* __restrict__ xt, const float* __restrict__ amask,
  const float* __restrict__ emb,
  const float* __restrict__ attn_W, const float* __restrict__ attn_b,
  const float* __restrict__ Wih_d, const float* __restrict__ Whh_d,
  const float* __restrict__ bih_d, const float* __restrict__ bhh_d,
  const float* __restrict__ gen_W, const float* __restrict__ gen_b,
  float* __restrict__ ws, float* __restrict__ out, int* __restrict__ bar, int t)
{
  __shared__ __align__(16) float x_lds[4096];
  __shared__ __align__(16) float h_lds[1024];
  __shared__ float w_lm[4], w_sm[4], w_ky[4];
  __shared__ int   w_ix[4];
  __shared__ float r_lm[256], r_sm[256], r_ky[256];
  __shared__ int   r_ix[256];
  __shared__ float attw[64], pcs[64];
  __shared__ float s_lmax, s_Z;
  __shared__ int   s_act, s_old;
  const int tid=threadIdx.x, b=blockIdx.x, wave=tid>>6, lane=tid&63;
  float* x_dec=ws+WS_X_DEC; float* h_dec=ws+WS_H_DEC; float* c_dec=ws+WS_C_DEC;
  float* dg=ws+WS_DGATES;   float* logits=ws+WS_LOGITS; float* parts=ws+WS_PARTS;
  float* enc_outs=ws+WS_ENC_OUTS; float* cenc=ws+WS_COPY_ENC;

  // ---- P1: gates GEMV (4096 x 4096) ----
  for(int j=tid;j<3072;j+=256) x_lds[j]=x_dec[j];
  {
    const float* hp=h_dec+((t+1)&1)*1024;   // h_{t-1}
    for(int j=tid;j<1024;j+=256) x_lds[3072+j]=hp[j];
  }
  __syncthreads();
  #pragma unroll
  for(int rr=0;rr<2;rr++){
    int r=b*8+wave*2+rr;
    const float* wr=Wih_d+(size_t)r*3072;
    float acc=0.0f;
    #pragma unroll
    for(int c4=0;c4<12;c4++){
      int m=c4*256+lane*4;
      acc += d4(*(const float4*)(wr+m), *(const float4*)(&x_lds[m]));
    }
    const float* hr=Whh_d+(size_t)r*1024;
    #pragma unroll
    for(int c4=0;c4<4;c4++){
      int m=c4*256+lane*4;
      acc += d4(*(const float4*)(hr+m), *(const float4*)(&x_lds[3072+m]));
    }
    acc=wred_sum(acc);
    if(lane==0) dg[r]=acc+bih_d[r]+bhh_d[r];
  }
  gridbar(bar, 51+t, (int)gridDim.x);

  // ---- P2: cell update (redundant per block) ----
  {
    const float* cp=c_dec+((t+1)&1)*1024;   // c_{t-1}
    float* cw=c_dec+(t&1)*1024;
    float* hw=h_dec+(t&1)*1024;
    for(int u=tid;u<1024;u+=256){
      float ig=dg[u], fg=dg[1024+u], gg=dg[2048+u], og=dg[3072+u];
      float c=sigm(fg)*cp[u]+sigm(ig)*tanhf(gg);
      float h=sigm(og)*tanhf(c);
      h_lds[u]=h;
      if(b==0){ cw[u]=c; hw[u]=h; out[(size_t)(t+1)*1024+u]=h; }  // states[t+1]
    }
  }
  __syncthreads();

  // ---- gen/copy GEMV + per-block online-softmax / masked-argmax partial ----
  {
    int rbase=-1;
    if(b<500) rbase=b*64+wave*16;           // gen rows
    else if(b==500) rbase=VOCAB+wave*16;    // copy rows
    float lm=-1e30f, sm=0.0f, ky=-1e30f; int ixx=0x7fffffff;
    if(rbase>=0){
      float lv[16];
      #pragma unroll
      for(int rr=0;rr<16;rr++){
        const float* wr = (b<500)? gen_W+(size_t)(rbase+rr)*1024
                                 : cenc +(size_t)(rbase-VOCAB+rr)*1024;
        float acc=0.0f;
        #pragma unroll
        for(int c4=0;c4<4;c4++){
          int m=c4*256+lane*4;
          acc += d4(*(const float4*)(wr+m), *(const float4*)(&h_lds[m]));
        }
        acc=wred_sum(acc);
        lv[rr] = (b<500)? acc+gen_b[rbase+rr] : acc;
      }
      #pragma unroll
      for(int rr=0;rr<16;rr++){
        int gi=rbase+rr;
        if(lane==0) logits[gi]=lv[rr];
        lm=fmaxf(lm,lv[rr]);
        float mk=amask[gi];
        float kk=(mk>0.0f)? (lv[rr]+__logf(mk)) : -1e30f;
        if(kk>ky){ ky=kk; ixx=gi; }       // strict >: first index wins on ties
      }
      #pragma unroll
      for(int rr=0;rr<16;rr++) sm+=__expf(lv[rr]-lm);
    }
    if(lane==0){ w_lm[wave]=lm; w_sm[wave]=sm; w_ky[wave]=ky; w_ix[wave]=ixx; }
    __syncthreads();
    if(tid==0){
      float lm2=w_lm[0], sm2=w_sm[0], ky2=w_ky[0]; int ix2=w_ix[0];
      for(int w=1;w<4;w++){
        float blm=w_lm[w], bsm=w_sm[w];
        if(blm>lm2){ sm2=sm2*__expf(lm2-blm)+bsm; lm2=blm; }
        else sm2 += bsm*__expf(blm-lm2);
        if(w_ky[w]>ky2 || (w_ky[w]==ky2 && w_ix[w]<ix2)){ ky2=w_ky[w]; ix2=w_ix[w]; }
      }
      float4 p; p.x=lm2; p.y=sm2; p.z=ky2; p.w=__int_as_float(ix2);
      *(float4*)(parts+(size_t)b*4)=p;
    }
  }

  // ---- ticket: last block finalizes + preps next step ----
  __syncthreads();
  if(tid==0){ __threadfence(); s_old=__hip_atomic_fetch_add(&bar[128+t],1,__ATOMIC_ACQ_REL,__HIP_MEMORY_SCOPE_AGENT); }
  __syncthreads();
  if(s_old!=(int)gridDim.x-1) return;
  if(tid==0) __threadfence();   // acquire side: invalidate caches, see all blocks' writes
  __syncthreads();

  // finalize step t: reduce 512 partials
  {
    float lm=-1e30f, sm=0.0f, ky=-1e30f; int ix=0x7fffffff;
    for(int i=tid;i<512;i+=256){
      const float4 p=*(const float4*)(parts+(size_t)i*4);
      if(p.x>lm){ sm=sm*__expf(lm-p.x)+p.y; lm=p.x; }
      else sm += p.y*__expf(p.x-lm);
      int pix=__float_as_int(p.w);
      if(p.z>ky || (p.z==ky && pix<ix)){ ky=p.z; ix=pix; }
    }
    r_lm[tid]=lm; r_sm[tid]=sm; r_ky[tid]=ky; r_ix[tid]=ix;
    __syncthreads();
    for(int s=128;s;s>>=1){
      if(tid<s){
        float blm=r_lm[tid+s], bsm=r_sm[tid+s];
        float alm=r_lm[tid],  a_sm=r_sm[tid];
        if(blm>alm){ r_sm[tid]=a_sm*__expf(alm-blm)+bsm; r_lm[tid]=blm; }
        else r_sm[tid]=a_sm+bsm*__expf(blm-alm);
        float bky=r_ky[tid+s]; int bix=r_ix[tid+s];
        if(bky>r_ky[tid] || (bky==r_ky[tid] && bix<r_ix[tid])){ r_ky[tid]=bky; r_ix[tid]=bix; }
      }
      __syncthreads();
    }
    if(tid==0){
      float lmax=r_lm[0], Z=r_sm[0];
      int aidx=(r_ky[0]<=-1e29f)?0:r_ix[0];
      bool isv=(aidx<VOCAB);
      int kcl=aidx-VOCAB; kcl=kcl<0?0:(kcl>(L-1)?(L-1):kcl);
      int sp=xt[kcl];
      int action=isv?aidx:sp;
      float prob=amask[aidx]*__expf(logits[aidx]-lmax)/Z;
      if(!isv){
        int a2=action<0?0:(action>(VOCAB-1)?(VOCAB-1):action);
        prob += amask[a2]*__expf(logits[a2]-lmax)/Z;
      }
      out[65*1024 + t]      = prob;
      out[65*1024 + 64 + t] = (float)action;
      s_lmax=lmax; s_Z=Z; s_act=action;
    }
  }
  __syncthreads();
  if(t==ML-1) return;

  // prep step t+1: pc, attention, x_dec
  const int action=s_act;
  if(tid<64){
    int k=tid;
    float v=__expf(logits[VOCAB+k]-s_lmax)/s_Z;
    int sp=(k<L)? xt[k] : -1;
    float m=(k>=1 && k<(L-1) && sp!=action)?1.0f:0.0f;
    float pv=v*m;
    float s=wred_sum(pv);
    pcs[k]=(s>0.0f)? pv/s : pv;
  }
  {
    int row = action<0 ? action+VOCAB : action;
    const float* er=emb+(size_t)row*EMBED;
    const float* hp=h_dec+(t&1)*1024;     // h_t
    for(int j=tid;j<1024;j+=256){ x_lds[j]=er[j]; x_lds[1024+j]=hp[j]; }
  }
  __syncthreads();
  for(int rr=0;rr<16;rr++){
    int r=wave*16+rr;
    const float* wr=attn_W+(size_t)r*2048;
    float acc=0.0f;
    #pragma unroll
    for(int c4=0;c4<4;c4++){
      int m=c4*256+lane*4;
      acc += d4(*(const float4*)(wr+m),      *(const float4*)(&x_lds[m]));
      acc += d4(*(const float4*)(wr+1024+m), *(const float4*)(&x_lds[1024+m]));
    }
    acc=wred_sum(acc);
    if(lane==0) attw[r]=acc+attn_b[r];
  }
  __syncthreads();
  if(tid<64){
    float v=attw[tid];
    float mx=wred_max(v);
    float e=__expf(v-mx);
    float s=wred_sum(e);
    attw[tid]=e/s;
  }
  __syncthreads();
  for(int j=tid;j<1024;j+=256){
    float aA=0.0f, aS=0.0f;
    for(int k=0;k<ML;k++){
      float e=enc_outs[(size_t)k*1024+j];
      aA += attw[k]*e;
      aS += pcs[k]*e;
    }
    x_dec[j]=x_lds[j];
    x_dec[1024+j]=aS;
    x_dec[2048+j]=aA;
  }
}

extern "C" void kernel_launch(void* const* d_in, const int* in_sizes, int n_in,
                              void* d_out, int out_size, void* d_ws, size_t ws_size,
                              hipStream_t stream)
{
  const int*   xt     = (const int*)d_in[0];
  const float* amask  = (const float*)d_in[1];
  const float* emb    = (const float*)d_in[2];
  const float* Wih_f  = (const float*)d_in[3];
  const float* Whh_f  = (const float*)d_in[4];
  const float* bih_f  = (const float*)d_in[5];
  const float* bhh_f  = (const float*)d_in[6];
  const float* Wih_b  = (const float*)d_in[7];
  const float* Whh_b  = (const float*)d_in[8];
  const float* bih_b  = (const float*)d_in[9];
  const float* bhh_b  = (const float*)d_in[10];
  const float* Wih_d  = (const float*)d_in[11];
  const float* Whh_d  = (const float*)d_in[12];
  const float* bih_d  = (const float*)d_in[13];
  const float* bhh_d  = (const float*)d_in[14];
  const float* attn_W = (const float*)d_in[15];
  const float* attn_b = (const float*)d_in[16];
  const float* gen_W  = (const float*)d_in[17];
  const float* gen_b  = (const float*)d_in[18];
  const float* copy_W = (const float*)d_in[19];
  const float* copy_b = (const float*)d_in[20];
  float* out=(float*)d_out;
  float* ws =(float*)d_ws;
  int*   bar=(int*)(ws+WS_BAR);

  hipMemsetAsync(bar, 0, 256*sizeof(int), stream);
  k_encoder<<<512,256,0,stream>>>(xt,emb,Wih_f,Whh_f,bih_f,bhh_f,Wih_b,Whh_b,bih_b,bhh_b,
                                  copy_W,copy_b,ws,out,bar);
  for(int t=0;t<ML;t++)
    k_dec_step<<<512,256,0,stream>>>(xt,amask,emb,attn_W,attn_b,Wih_d,Whh_d,bih_d,bhh_d,
                                     gen_W,gen_b,ws,out,bar,t);
}

// Round 3
// 8170.098 us; speedup vs baseline: 1.7831x; 1.7831x over previous
//
#include <hip/hip_runtime.h>
#include <math.h>

#define L 50
#define ML 64
#define VOCAB 32000
#define EMBED 1024
#define HID 1024
#define HH 512
#define TOT (VOCAB+ML)
#define NPART 501

// workspace layout (float offsets)
#define WS_ENC_GATES 0        // [2][4096]
#define WS_C_ENC     8192     // [2][1024]
#define WS_ENC_OUTS  10240    // [64][1024]
#define WS_COPY_ENC  75776    // [64][1024]
#define WS_H_DEC     141312   // [2][1024]
#define WS_C_DEC     143360   // [2][1024]
#define WS_X_DEC     145408   // [3072]
#define WS_DGATES    148480   // [4096]
#define WS_LOGITS    152576   // [32064]
#define WS_PARTS     184640   // [501*4] {lmax,sumexp,bestkey,bestidx}

__device__ __forceinline__ float wred_sum(float v){
  #pragma unroll
  for(int o=32;o;o>>=1) v += __shfl_xor(v,o,64);
  return v;
}
__device__ __forceinline__ float wred_max(float v){
  #pragma unroll
  for(int o=32;o;o>>=1) v = fmaxf(v,__shfl_xor(v,o,64));
  return v;
}
__device__ __forceinline__ float sigm(float x){ return 1.0f/(1.0f+__expf(-x)); }
__device__ __forceinline__ float d4(float4 a, float4 b){ return a.x*b.x + a.y*b.y + a.z*b.z + a.w*b.w; }

// ---------------- encoder step: redundant cell-update(t-1) + gates GEMV(t) ----------------
__global__ __launch_bounds__(256) void k_enc_step(
  const int* __restrict__ xt, const float* __restrict__ emb,
  const float* __restrict__ Wih_f, const float* __restrict__ Whh_f,
  const float* __restrict__ bih_f, const float* __restrict__ bhh_f,
  const float* __restrict__ Wih_b, const float* __restrict__ Whh_b,
  const float* __restrict__ bih_b, const float* __restrict__ bhh_b,
  float* __restrict__ ws, int t)
{
  __shared__ __align__(16) float h_lds[1024];   // [hf(512), hb(512)]
  __shared__ __align__(16) float xe[1024];
  const int tid = threadIdx.x;
  float* gates   = ws + WS_ENC_GATES;
  float* c_enc   = ws + WS_C_ENC;
  float* enc_outs= ws + WS_ENC_OUTS;
  {
    const int tok = xt[t];
    const float* er = emb + (size_t)tok*EMBED;
    for(int j=tid;j<1024;j+=256) xe[j]=er[j];
  }
  if(t>0){
    const float* gp = gates + ((t-1)&1)*4096;
    const float* cp = c_enc + (t&1)*1024;        // c_{t-2}
    float* cw = c_enc + ((t-1)&1)*1024;          // c_{t-1}
    for(int u=tid;u<1024;u+=256){
      int base = (u<512)?0:2048;
      int uu   = (u<512)?u:(u-512);
      float ig=gp[base+uu], fg=gp[base+512+uu], gg=gp[base+1024+uu], og=gp[base+1536+uu];
      float cprev = (t==1)?0.0f:cp[u];
      float c = sigm(fg)*cprev + sigm(ig)*tanhf(gg);
      float h = sigm(og)*tanhf(c);
      h_lds[u]=h;
      if(blockIdx.x==0){
        cw[u]=c;
        enc_outs[(size_t)(t-1)*1024+u]=h;
      }
    }
  }
  __syncthreads();
  float* gw = gates + (t&1)*4096;
  const int wave=tid>>6, lane=tid&63;
  for(int rr=0;rr<2;rr++){
    int r = blockIdx.x*8 + wave*2 + rr;          // 0..4095
    bool isF = (r<2048);
    int rl = isF? r : r-2048;
    const float* Wih = isF? Wih_f : Wih_b;
    const float* Whh = isF? Whh_f : Whh_b;
    float bias = isF? (bih_f[rl]+bhh_f[rl]) : (bih_b[rl]+bhh_b[rl]);
    const float* wr = Wih + (size_t)rl*EMBED;
    float acc=0.0f;
    #pragma unroll
    for(int c4=0;c4<4;c4++){
      int m=c4*256+lane*4;
      acc += d4(*(const float4*)(wr+m), *(const float4*)(&xe[m]));
    }
    if(t>0){
      const float* hr = Whh + (size_t)rl*HH;
      const float* hs = &h_lds[isF?0:512];
      #pragma unroll
      for(int c4=0;c4<2;c4++){
        int m=c4*256+lane*4;
        acc += d4(*(const float4*)(hr+m), *(const float4*)(&hs[m]));
      }
    }
    acc = wred_sum(acc);
    if(lane==0) gw[r]=acc+bias;
  }
}

// ---------------- encoder final: h_49,c_49 -> enc_outs[49], h0/c0, states[0], zero pad ----------------
__global__ __launch_bounds__(256) void k_enc_final(float* __restrict__ ws, float* __restrict__ out)
{
  const int tid=threadIdx.x;
  float* gates = ws + WS_ENC_GATES;
  float* c_enc = ws + WS_C_ENC;
  float* enc_outs = ws + WS_ENC_OUTS;
  float* h_dec = ws + WS_H_DEC;
  float* c_dec = ws + WS_C_DEC;
  const float* gp = gates + ((L-1)&1)*4096;  // gates_49
  const float* cp = c_enc + ((L-2)&1)*1024;  // c_48
  for(int u=tid;u<1024;u+=256){
    int base=(u<512)?0:2048;
    int uu=(u<512)?u:(u-512);
    float ig=gp[base+uu], fg=gp[base+512+uu], gg=gp[base+1024+uu], og=gp[base+1536+uu];
    float c = sigm(fg)*cp[u] + sigm(ig)*tanhf(gg);
    float h = sigm(og)*tanhf(c);
    enc_outs[(size_t)(L-1)*1024+u]=h;
    h_dec[1024+u]=h;     // h0 -> buffer 1 (read as h_{-1})
    c_dec[1024+u]=c;     // c0 -> buffer 1
    out[u]=h;            // states[0]
  }
  for(int j=tid;j<(ML-L)*1024;j+=256) enc_outs[(size_t)L*1024+j]=0.0f;
}

// ---------------- copy_enc = tanh(enc_outs @ copy_W^T + copy_b) ----------------
// 256 blocks x 4 waves, one output row j per wave (16x more parallel than r1)
__global__ __launch_bounds__(256) void k_copy_enc(
  const float* __restrict__ copy_W, const float* __restrict__ copy_b, float* __restrict__ ws)
{
  float* enc_outs = ws+WS_ENC_OUTS;
  float* cenc = ws+WS_COPY_ENC;
  const int wave=threadIdx.x>>6, lane=threadIdx.x&63;
  int j = blockIdx.x*4 + wave;   // 0..1023
  const float* wr = copy_W + (size_t)j*1024;
  float4 w0=*(const float4*)(wr+0*256+lane*4);
  float4 w1=*(const float4*)(wr+1*256+lane*4);
  float4 w2=*(const float4*)(wr+2*256+lane*4);
  float4 w3=*(const float4*)(wr+3*256+lane*4);
  float bj = copy_b[j];
  for(int k=0;k<ML;k++){
    const float* er = enc_outs + (size_t)k*1024;
    float acc = d4(w0,*(const float4*)(er+0*256+lane*4))
              + d4(w1,*(const float4*)(er+1*256+lane*4))
              + d4(w2,*(const float4*)(er+2*256+lane*4))
              + d4(w3,*(const float4*)(er+3*256+lane*4));
    acc = wred_sum(acc);
    if(lane==0) cenc[(size_t)k*1024+j]=tanhf(acc+bj);
  }
}

// ---------------- decoder pre-kernel (1 block): finalize step t-1, prep x_dec for step t ----------------
__global__ __launch_bounds__(256) void k_dec_pre(
  const int* __restrict__ xt, const float* __restrict__ amask,
  const float* __restrict__ emb,
  const float* __restrict__ attn_W, const float* __restrict__ attn_b,
  float* __restrict__ ws, float* __restrict__ out, int t)
{
  __shared__ __align__(16) float dec_in[1024];
  __shared__ __align__(16) float hprev[1024];
  __shared__ float pc[64];
  __shared__ float attw[64];
  __shared__ float r_lm[256], r_sm[256], r_ky[256];
  __shared__ int r_ix[256];
  __shared__ float s_lmax, s_Z;
  __shared__ int s_act;
  const int tid=threadIdx.x;
  float* h_dec=ws+WS_H_DEC; float* x_dec=ws+WS_X_DEC;
  float* logits=ws+WS_LOGITS; float* parts=ws+WS_PARTS;
  float* enc_outs=ws+WS_ENC_OUTS;

  if(t==0){
    for(int j=tid;j<1024;j+=256){
      x_dec[j]=emb[j];          // sos = embedding[0]
      x_dec[1024+j]=0.0f;       // selective = 0 (first)
      x_dec[2048+j]=0.0f;       // attentive = 0 (first)
    }
    return;
  }
  // ---- finalize step t-1: reduce block partials ----
  {
    float lm=-INFINITY, sm=0.0f, ky=-INFINITY; int ix=0x7fffffff;
    for(int i=tid;i<NPART;i+=256){
      const float4 p = *(const float4*)(parts+(size_t)i*4);
      float plm=p.x, psm=p.y, pky=p.z; int pix=__float_as_int(p.w);
      if(plm>lm){ sm = sm*__expf(lm-plm)+psm; lm=plm; }
      else sm += psm*__expf(plm-lm);
      if(pky>ky || (pky==ky && pix<ix)){ ky=pky; ix=pix; }
    }
    r_lm[tid]=lm; r_sm[tid]=sm; r_ky[tid]=ky; r_ix[tid]=ix;
    __syncthreads();
    for(int s=128;s;s>>=1){
      if(tid<s){
        float blm=r_lm[tid+s], bsm=r_sm[tid+s];
        float alm=r_lm[tid], a_sm=r_sm[tid];
        if(blm>alm){ r_sm[tid]=a_sm*__expf(alm-blm)+bsm; r_lm[tid]=blm; }
        else r_sm[tid]=a_sm+bsm*__expf(blm-alm);
        float bky=r_ky[tid+s]; int bix=r_ix[tid+s];
        if(bky>r_ky[tid] || (bky==r_ky[tid] && bix<r_ix[tid])){ r_ky[tid]=bky; r_ix[tid]=bix; }
      }
      __syncthreads();
    }
    if(tid==0){
      float lmax=r_lm[0]; float Z=r_sm[0];
      float bky=r_ky[0];
      int aidx = (bky==-INFINITY)?0:r_ix[0];
      bool isv = aidx<VOCAB;
      int kcl = aidx-VOCAB; kcl = kcl<0?0:(kcl>(L-1)?(L-1):kcl);
      int sp = xt[kcl];                 // kcl in [0,49] -> sent_pad = x_tokens
      int action = isv? aidx : sp;
      float prob = amask[aidx]*__expf(logits[aidx]-lmax)/Z;
      if(!isv){
        int a2 = action<0?0:(action>(VOCAB-1)?(VOCAB-1):action);
        prob += amask[a2]*__expf(logits[a2]-lmax)/Z;
      }
      out[65*1024 + (t-1)] = prob;
      out[65*1024 + 64 + (t-1)] = (float)action;
      s_lmax=lmax; s_Z=Z; s_act=action;
    }
  }
  __syncthreads();
  if(t==ML) return;   // nothing more after last step

  const int action = s_act;
  // pc = normalize(mask * probs[VOCAB:])
  if(tid<64){
    int k=tid;
    float v=__expf(logits[VOCAB+k]-s_lmax)/s_Z;
    int sp=(k<L)? xt[k] : -1;
    float m=(k>=1 && k<(L-1) && sp!=action)?1.0f:0.0f;
    float pv=v*m;
    float s=wred_sum(pv);
    pc[k]=(s>0.0f)? pv/s : pv;
  }
  {
    int row = action<0 ? action+VOCAB : action;  // jnp negative-index wrap
    const float* er = emb + (size_t)row*EMBED;
    const float* hp = h_dec + ((t-1)&1)*1024;
    for(int j=tid;j<1024;j+=256){ dec_in[j]=er[j]; hprev[j]=hp[j]; }
  }
  __syncthreads();
  // attention logits (64 rows x 2048)
  const int wave=tid>>6, lane=tid&63;
  for(int rr=0;rr<16;rr++){
    int r=wave*16+rr;
    const float* wr = attn_W + (size_t)r*2048;
    float acc=0.0f;
    #pragma unroll
    for(int c4=0;c4<4;c4++){
      int m=c4*256+lane*4;
      acc += d4(*(const float4*)(wr+m),      *(const float4*)(&dec_in[m]));
      acc += d4(*(const float4*)(wr+1024+m), *(const float4*)(&hprev[m]));
    }
    acc=wred_sum(acc);
    if(lane==0) attw[r]=acc+attn_b[r];
  }
  __syncthreads();
  if(tid<64){
    float v=attw[tid];
    float mx=wred_max(v);
    float e=__expf(v-mx);
    float s=wred_sum(e);
    attw[tid]=e/s;
  }
  __syncthreads();
  // attentive / selective + write x_dec = [dec_in, selective, attentive]
  for(int j=tid;j<1024;j+=256){
    float aA=0.0f,aS=0.0f;
    for(int k=0;k<ML;k++){
      float e=enc_outs[(size_t)k*1024+j];
      aA += attw[k]*e;
      aS += pc[k]*e;
    }
    x_dec[j]=dec_in[j];
    x_dec[1024+j]=aS;
    x_dec[2048+j]=aA;
  }
}

// ---------------- decoder gates GEMV: 4096 x (3072 + 1024) ----------------
__global__ __launch_bounds__(256) void k_dec_gates(
  const float* __restrict__ Wih_d, const float* __restrict__ Whh_d,
  const float* __restrict__ bih_d, const float* __restrict__ bhh_d,
  float* __restrict__ ws, int t)
{
  __shared__ __align__(16) float x_lds[4096];
  const int tid=threadIdx.x;
  float* x_dec=ws+WS_X_DEC; float* h_dec=ws+WS_H_DEC; float* dg=ws+WS_DGATES;
  for(int j=tid;j<3072;j+=256) x_lds[j]=x_dec[j];
  {
    const float* hp=h_dec+((t+1)&1)*1024;   // h_{t-1}
    for(int j=tid;j<1024;j+=256) x_lds[3072+j]=hp[j];
  }
  __syncthreads();
  const int wave=tid>>6, lane=tid&63;
  for(int rr=0;rr<2;rr++){
    int r=blockIdx.x*8+wave*2+rr;
    const float* wr=Wih_d+(size_t)r*3072;
    float acc=0.0f;
    #pragma unroll
    for(int c4=0;c4<12;c4++){
      int m=c4*256+lane*4;
      acc += d4(*(const float4*)(wr+m), *(const float4*)(&x_lds[m]));
    }
    const float* hr=Whh_d+(size_t)r*1024;
    #pragma unroll
    for(int c4=0;c4<4;c4++){
      int m=c4*256+lane*4;
      acc += d4(*(const float4*)(hr+m), *(const float4*)(&x_lds[3072+m]));
    }
    acc=wred_sum(acc);
    if(lane==0) dg[r]=acc+bih_d[r]+bhh_d[r];
  }
}

// ---------------- decoder gen: redundant cell update + gen/copy GEMV + softmax partials ----------------
// 501 blocks: b<500 -> 64 gen rows each (16/wave); b==500 -> 64 copy rows
__global__ __launch_bounds__(256) void k_dec_gen(
  const float* __restrict__ gen_W, const float* __restrict__ gen_b,
  const float* __restrict__ amask,
  float* __restrict__ ws, float* __restrict__ out, int t)
{
  __shared__ __align__(16) float h_lds[1024];
  __shared__ float w_lm[4], w_sm[4], w_ky[4];
  __shared__ int w_ix[4];
  const int tid=threadIdx.x;
  float* dg=ws+WS_DGATES;
  float* c_dec=ws+WS_C_DEC; float* h_dec=ws+WS_H_DEC;
  float* logits=ws+WS_LOGITS; float* parts=ws+WS_PARTS;
  float* cenc=ws+WS_COPY_ENC;
  {
    const float* cp=c_dec+((t+1)&1)*1024;   // c_{t-1}
    float* cw=c_dec+(t&1)*1024;
    float* hw=h_dec+(t&1)*1024;
    for(int u=tid;u<1024;u+=256){
      float ig=dg[u], fg=dg[1024+u], gg=dg[2048+u], og=dg[3072+u];
      float c=sigm(fg)*cp[u]+sigm(ig)*tanhf(gg);
      float h=sigm(og)*tanhf(c);
      h_lds[u]=h;
      if(blockIdx.x==0){ cw[u]=c; hw[u]=h; out[(size_t)(t+1)*1024+u]=h; }  // states[t+1]
    }
  }
  __syncthreads();
  const int wave=tid>>6, lane=tid&63;
  const int b=blockIdx.x;
  const bool isGen=(b<500);
  const int rbase = isGen ? (b*64+wave*16) : (VOCAB+wave*16);
  float lv[16];
  #pragma unroll
  for(int rr=0;rr<16;rr++){
    const float* wr = isGen ? gen_W+(size_t)(rbase+rr)*1024
                            : cenc +(size_t)(rbase-VOCAB+rr)*1024;
    float acc=0.0f;
    #pragma unroll
    for(int c4=0;c4<4;c4++){
      int m=c4*256+lane*4;
      acc += d4(*(const float4*)(wr+m), *(const float4*)(&h_lds[m]));
    }
    acc=wred_sum(acc);
    lv[rr] = isGen ? acc+gen_b[rbase+rr] : acc;
  }
  if(lane==0){
    float lm=-INFINITY, ky=-INFINITY; int ix=0;
    #pragma unroll
    for(int rr=0;rr<16;rr++){
      int gi=rbase+rr;
      logits[gi]=lv[rr];
      lm=fmaxf(lm,lv[rr]);
      float mk=amask[gi];
      float kk = (mk>0.0f)? (lv[rr]+__logf(mk)) : -INFINITY;
      if(kk>ky){ ky=kk; ix=gi; }   // strict > keeps first index on ties
    }
    float sm=0.0f;
    #pragma unroll
    for(int rr=0;rr<16;rr++) sm += __expf(lv[rr]-lm);
    w_lm[wave]=lm; w_sm[wave]=sm; w_ky[wave]=ky; w_ix[wave]=ix;
  }
  __syncthreads();
  if(tid==0){
    float lm=w_lm[0], sm=w_sm[0], ky=w_ky[0]; int ix=w_ix[0];
    for(int w=1;w<4;w++){
      float blm=w_lm[w], bsm=w_sm[w];
      if(blm>lm){ sm=sm*__expf(lm-blm)+bsm; lm=blm; }
      else sm += bsm*__expf(blm-lm);
      if(w_ky[w]>ky || (w_ky[w]==ky && w_ix[w]<ix)){ ky=w_ky[w]; ix=w_ix[w]; }
    }
    float4 p; p.x=lm; p.y=sm; p.z=ky; p.w=__int_as_float(ix);
    *(float4*)(parts+(size_t)blockIdx.x*4)=p;
  }
}

extern "C" void kernel_launch(void* const* d_in, const int* in_sizes, int n_in,
                              void* d_out, int out_size, void* d_ws, size_t ws_size,
                              hipStream_t stream)
{
  const int*   xt     = (const int*)d_in[0];
  const float* amask  = (const float*)d_in[1];
  const float* emb    = (const float*)d_in[2];
  const float* Wih_f  = (const float*)d_in[3];
  const float* Whh_f  = (const float*)d_in[4];
  const float* bih_f  = (const float*)d_in[5];
  const float* bhh_f  = (const float*)d_in[6];
  const float* Wih_b  = (const float*)d_in[7];
  const float* Whh_b  = (const float*)d_in[8];
  const float* bih_b  = (const float*)d_in[9];
  const float* bhh_b  = (const float*)d_in[10];
  const float* Wih_d  = (const float*)d_in[11];
  const float* Whh_d  = (const float*)d_in[12];
  const float* bih_d  = (const float*)d_in[13];
  const float* bhh_d  = (const float*)d_in[14];
  const float* attn_W = (const float*)d_in[15];
  const float* attn_b = (const float*)d_in[16];
  const float* gen_W  = (const float*)d_in[17];
  const float* gen_b  = (const float*)d_in[18];
  const float* copy_W = (const float*)d_in[19];
  const float* copy_b = (const float*)d_in[20];
  float* out=(float*)d_out;
  float* ws =(float*)d_ws;

  for(int t=0;t<L;t++)
    k_enc_step<<<512,256,0,stream>>>(xt,emb,Wih_f,Whh_f,bih_f,bhh_f,Wih_b,Whh_b,bih_b,bhh_b,ws,t);
  k_enc_final<<<1,256,0,stream>>>(ws,out);
  k_copy_enc<<<256,256,0,stream>>>(copy_W,copy_b,ws);
  for(int t=0;t<ML;t++){
    k_dec_pre  <<<1,256,0,stream>>>(xt,amask,emb,attn_W,attn_b,ws,out,t);
    k_dec_gates<<<512,256,0,stream>>>(Wih_d,Whh_d,bih_d,bhh_d,ws,t);
    k_dec_gen  <<<501,256,0,stream>>>(gen_W,gen_b,amask,ws,out,t);
  }
  k_dec_pre<<<1,256,0,stream>>>(xt,amask,emb,attn_W,attn_b,ws,out,ML);
}

// Round 4
// 3727.993 us; speedup vs baseline: 3.9077x; 2.1916x over previous
//
#include <hip/hip_runtime.h>
#include <math.h>

#define L 50
#define ML 64
#define VOCAB 32000
#define EMBED 1024
#define HID 1024
#define HH 512
#define TOT (VOCAB+ML)
#define NPART 501

// workspace layout (float offsets)
#define WS_ENC_GATES 0        // [2][4096]
#define WS_C_ENC     8192     // [2][1024]
#define WS_ENC_OUTS  10240    // [64][1024]
#define WS_COPY_ENC  75776    // [64][1024]
#define WS_H_DEC     141312   // [2][1024]
#define WS_C_DEC     143360   // [2][1024]
#define WS_X_DEC     145408   // [3072]
#define WS_DGATES    148480   // [4096]
#define WS_LOGITS    152576   // [32064]
#define WS_PARTS     184640   // [501*4] {lmax,sumexp,bestkey,bestidx}
#define WS_ATTW      186688   // [64] raw attention logits
#define WS_PC        186752   // [64] selective-read weights

__device__ __forceinline__ float wred_sum(float v){
  #pragma unroll
  for(int o=32;o;o>>=1) v += __shfl_xor(v,o,64);
  return v;
}
__device__ __forceinline__ float wred_max(float v){
  #pragma unroll
  for(int o=32;o;o>>=1) v = fmaxf(v,__shfl_xor(v,o,64));
  return v;
}
__device__ __forceinline__ float sigm(float x){ return 1.0f/(1.0f+__expf(-x)); }
__device__ __forceinline__ float d4(float4 a, float4 b){ return a.x*b.x + a.y*b.y + a.z*b.z + a.w*b.w; }

// ---------------- encoder step: redundant cell-update(t-1) + gates GEMV(t) ----------------
__global__ __launch_bounds__(256) void k_enc_step(
  const int* __restrict__ xt, const float* __restrict__ emb,
  const float* __restrict__ Wih_f, const float* __restrict__ Whh_f,
  const float* __restrict__ bih_f, const float* __restrict__ bhh_f,
  const float* __restrict__ Wih_b, const float* __restrict__ Whh_b,
  const float* __restrict__ bih_b, const float* __restrict__ bhh_b,
  float* __restrict__ ws, int t)
{
  __shared__ __align__(16) float h_lds[1024];   // [hf(512), hb(512)]
  __shared__ __align__(16) float xe[1024];
  const int tid = threadIdx.x;
  float* gates   = ws + WS_ENC_GATES;
  float* c_enc   = ws + WS_C_ENC;
  float* enc_outs= ws + WS_ENC_OUTS;
  {
    const int tok = xt[t];
    const float* er = emb + (size_t)tok*EMBED;
    for(int j=tid;j<1024;j+=256) xe[j]=er[j];
  }
  if(t>0){
    const float* gp = gates + ((t-1)&1)*4096;
    const float* cp = c_enc + (t&1)*1024;        // c_{t-2}
    float* cw = c_enc + ((t-1)&1)*1024;          // c_{t-1}
    for(int u=tid;u<1024;u+=256){
      int base = (u<512)?0:2048;
      int uu   = (u<512)?u:(u-512);
      float ig=gp[base+uu], fg=gp[base+512+uu], gg=gp[base+1024+uu], og=gp[base+1536+uu];
      float cprev = (t==1)?0.0f:cp[u];
      float c = sigm(fg)*cprev + sigm(ig)*tanhf(gg);
      float h = sigm(og)*tanhf(c);
      h_lds[u]=h;
      if(blockIdx.x==0){
        cw[u]=c;
        enc_outs[(size_t)(t-1)*1024+u]=h;
      }
    }
  }
  __syncthreads();
  float* gw = gates + (t&1)*4096;
  const int wave=tid>>6, lane=tid&63;
  for(int rr=0;rr<2;rr++){
    int r = blockIdx.x*8 + wave*2 + rr;          // 0..4095
    bool isF = (r<2048);
    int rl = isF? r : r-2048;
    const float* Wih = isF? Wih_f : Wih_b;
    const float* Whh = isF? Whh_f : Whh_b;
    float bias = isF? (bih_f[rl]+bhh_f[rl]) : (bih_b[rl]+bhh_b[rl]);
    const float* wr = Wih + (size_t)rl*EMBED;
    float acc=0.0f;
    #pragma unroll
    for(int c4=0;c4<4;c4++){
      int m=c4*256+lane*4;
      acc += d4(*(const float4*)(wr+m), *(const float4*)(&xe[m]));
    }
    if(t>0){
      const float* hr = Whh + (size_t)rl*HH;
      const float* hs = &h_lds[isF?0:512];
      #pragma unroll
      for(int c4=0;c4<2;c4++){
        int m=c4*256+lane*4;
        acc += d4(*(const float4*)(hr+m), *(const float4*)(&hs[m]));
      }
    }
    acc = wred_sum(acc);
    if(lane==0) gw[r]=acc+bias;
  }
}

// ---------------- encoder final: h_49,c_49 -> enc_outs[49], h0/c0, states[0], zero pad ----------------
__global__ __launch_bounds__(256) void k_enc_final(float* __restrict__ ws, float* __restrict__ out)
{
  const int tid=threadIdx.x;
  float* gates = ws + WS_ENC_GATES;
  float* c_enc = ws + WS_C_ENC;
  float* enc_outs = ws + WS_ENC_OUTS;
  float* h_dec = ws + WS_H_DEC;
  float* c_dec = ws + WS_C_DEC;
  const float* gp = gates + ((L-1)&1)*4096;  // gates_49
  const float* cp = c_enc + ((L-2)&1)*1024;  // c_48
  for(int u=tid;u<1024;u+=256){
    int base=(u<512)?0:2048;
    int uu=(u<512)?u:(u-512);
    float ig=gp[base+uu], fg=gp[base+512+uu], gg=gp[base+1024+uu], og=gp[base+1536+uu];
    float c = sigm(fg)*cp[u] + sigm(ig)*tanhf(gg);
    float h = sigm(og)*tanhf(c);
    enc_outs[(size_t)(L-1)*1024+u]=h;
    h_dec[1024+u]=h;     // h0 -> buffer 1 (read as h_{-1})
    c_dec[1024+u]=c;     // c0 -> buffer 1
    out[u]=h;            // states[0]
  }
  for(int j=tid;j<(ML-L)*1024;j+=256) enc_outs[(size_t)L*1024+j]=0.0f;
}

// ---------------- copy_enc = tanh(enc_outs @ copy_W^T + copy_b) ----------------
__global__ __launch_bounds__(256) void k_copy_enc(
  const float* __restrict__ copy_W, const float* __restrict__ copy_b, float* __restrict__ ws)
{
  float* enc_outs = ws+WS_ENC_OUTS;
  float* cenc = ws+WS_COPY_ENC;
  const int wave=threadIdx.x>>6, lane=threadIdx.x&63;
  int j = blockIdx.x*4 + wave;   // 0..1023
  const float* wr = copy_W + (size_t)j*1024;
  float4 w0=*(const float4*)(wr+0*256+lane*4);
  float4 w1=*(const float4*)(wr+1*256+lane*4);
  float4 w2=*(const float4*)(wr+2*256+lane*4);
  float4 w3=*(const float4*)(wr+3*256+lane*4);
  float bj = copy_b[j];
  for(int k=0;k<ML;k++){
    const float* er = enc_outs + (size_t)k*1024;
    float acc = d4(w0,*(const float4*)(er+0*256+lane*4))
              + d4(w1,*(const float4*)(er+1*256+lane*4))
              + d4(w2,*(const float4*)(er+2*256+lane*4))
              + d4(w3,*(const float4*)(er+3*256+lane*4));
    acc = wred_sum(acc);
    if(lane==0) cenc[(size_t)k*1024+j]=tanhf(acc+bj);
  }
}

// ---------------- decoder t=0 init ----------------
__global__ __launch_bounds__(256) void k_dec_init(const float* __restrict__ emb, float* __restrict__ ws)
{
  float* x_dec=ws+WS_X_DEC;
  for(int j=threadIdx.x;j<1024;j+=256){
    x_dec[j]=emb[j];          // sos = embedding[0]
    x_dec[1024+j]=0.0f;       // selective (first)
    x_dec[2048+j]=0.0f;       // attentive (first)
  }
}

// ---------------- k_attn: finalize step t-1 (all blocks redundant) + attention row per block ----------------
// grid=64 (or 1 with fin_only=1). Block b: wave 0 computes attention logit row b.
__global__ __launch_bounds__(256) void k_attn(
  const int* __restrict__ xt, const float* __restrict__ amask,
  const float* __restrict__ emb,
  const float* __restrict__ attn_W, const float* __restrict__ attn_b,
  float* __restrict__ ws, float* __restrict__ out, int t, int fin_only)
{
  __shared__ __align__(16) float dec_in[1024];
  __shared__ __align__(16) float hprev[1024];
  __shared__ float r_lm[256], r_sm[256], r_ky[256];
  __shared__ int r_ix[256];
  __shared__ float s_lmax, s_Z;
  __shared__ int s_act;
  const int tid=threadIdx.x;
  float* h_dec=ws+WS_H_DEC; float* x_dec=ws+WS_X_DEC;
  float* logits=ws+WS_LOGITS; float* parts=ws+WS_PARTS;
  float* attw_raw=ws+WS_ATTW; float* pcw=ws+WS_PC;

  // ---- finalize step t-1: reduce block partials (every block, identical math) ----
  {
    float lm=-INFINITY, sm=0.0f, ky=-INFINITY; int ix=0x7fffffff;
    for(int i=tid;i<NPART;i+=256){
      const float4 p = *(const float4*)(parts+(size_t)i*4);
      float plm=p.x, psm=p.y, pky=p.z; int pix=__float_as_int(p.w);
      if(plm>lm){ sm = sm*__expf(lm-plm)+psm; lm=plm; }
      else sm += psm*__expf(plm-lm);
      if(pky>ky || (pky==ky && pix<ix)){ ky=pky; ix=pix; }
    }
    r_lm[tid]=lm; r_sm[tid]=sm; r_ky[tid]=ky; r_ix[tid]=ix;
    __syncthreads();
    for(int s=128;s;s>>=1){
      if(tid<s){
        float blm=r_lm[tid+s], bsm=r_sm[tid+s];
        float alm=r_lm[tid], a_sm=r_sm[tid];
        if(blm>alm){ r_sm[tid]=a_sm*__expf(alm-blm)+bsm; r_lm[tid]=blm; }
        else r_sm[tid]=a_sm+bsm*__expf(blm-alm);
        float bky=r_ky[tid+s]; int bix=r_ix[tid+s];
        if(bky>r_ky[tid] || (bky==r_ky[tid] && bix<r_ix[tid])){ r_ky[tid]=bky; r_ix[tid]=bix; }
      }
      __syncthreads();
    }
    if(tid==0){
      float lmax=r_lm[0]; float Z=r_sm[0];
      float bky=r_ky[0];
      int aidx = (bky==-INFINITY)?0:r_ix[0];
      bool isv = aidx<VOCAB;
      int kcl = aidx-VOCAB; kcl = kcl<0?0:(kcl>(L-1)?(L-1):kcl);
      int sp = xt[kcl];
      int action = isv? aidx : sp;
      if(blockIdx.x==0){
        float prob = amask[aidx]*__expf(logits[aidx]-lmax)/Z;
        if(!isv){
          int a2 = action<0?0:(action>(VOCAB-1)?(VOCAB-1):action);
          prob += amask[a2]*__expf(logits[a2]-lmax)/Z;
        }
        out[65*1024 + (t-1)] = prob;
        out[65*1024 + 64 + (t-1)] = (float)action;
      }
      s_lmax=lmax; s_Z=Z; s_act=action;
    }
  }
  __syncthreads();
  if(fin_only) return;

  const int action = s_act;
  // pc (block 0 only; identical math to round 3)
  if(blockIdx.x==0 && tid<64){
    int k=tid;
    float v=__expf(logits[VOCAB+k]-s_lmax)/s_Z;
    int sp=(k<L)? xt[k] : -1;
    float m=(k>=1 && k<(L-1) && sp!=action)?1.0f:0.0f;
    float pv=v*m;
    float s=wred_sum(pv);
    pcw[k]=(s>0.0f)? pv/s : pv;
  }
  // load dec_in (emb[action]) + h_{t-1} into LDS
  {
    int row = action<0 ? action+VOCAB : action;
    const float* er = emb + (size_t)row*EMBED;
    const float* hp = h_dec + ((t-1)&1)*1024;
    for(int j=tid;j<1024;j+=256){
      float v=er[j];
      dec_in[j]=v; hprev[j]=hp[j];
      if(blockIdx.x==0) x_dec[j]=v;
    }
  }
  __syncthreads();
  // wave 0 computes attention logit row r=blockIdx.x (identical per-row math)
  if(tid<64){
    const int lane=tid;
    const float* wr = attn_W + (size_t)blockIdx.x*2048;
    float acc=0.0f;
    #pragma unroll
    for(int c4=0;c4<4;c4++){
      int m=c4*256+lane*4;
      acc += d4(*(const float4*)(wr+m),      *(const float4*)(&dec_in[m]));
      acc += d4(*(const float4*)(wr+1024+m), *(const float4*)(&hprev[m]));
    }
    acc=wred_sum(acc);
    if(lane==0) attw_raw[blockIdx.x]=acc+attn_b[blockIdx.x];
  }
}

// ---------------- k_prep: softmax(attw) + x_dec[1024:3072] (4 blocks x 256, thread=one j) ----------------
__global__ __launch_bounds__(256) void k_prep(float* __restrict__ ws)
{
  __shared__ float attw_s[64], pc_s[64];
  const int tid=threadIdx.x;
  float* enc_outs=ws+WS_ENC_OUTS; float* x_dec=ws+WS_X_DEC;
  float* attw_raw=ws+WS_ATTW; float* pcw=ws+WS_PC;
  if(tid<64){
    float v=attw_raw[tid];
    float mx=wred_max(v);
    float e=__expf(v-mx);
    float s=wred_sum(e);
    attw_s[tid]=e/s;
    pc_s[tid]=pcw[tid];
  }
  __syncthreads();
  int j=blockIdx.x*256+tid;
  float aA=0.0f, aS=0.0f;
  for(int k=0;k<ML;k++){
    float e=enc_outs[(size_t)k*1024+j];
    aA += attw_s[k]*e;
    aS += pc_s[k]*e;
  }
  x_dec[1024+j]=aS;
  x_dec[2048+j]=aA;
}

// ---------------- decoder gates GEMV: 4096 x (3072 + 1024) ----------------
__global__ __launch_bounds__(256) void k_dec_gates(
  const float* __restrict__ Wih_d, const float* __restrict__ Whh_d,
  const float* __restrict__ bih_d, const float* __restrict__ bhh_d,
  float* __restrict__ ws, int t)
{
  __shared__ __align__(16) float x_lds[4096];
  const int tid=threadIdx.x;
  float* x_dec=ws+WS_X_DEC; float* h_dec=ws+WS_H_DEC; float* dg=ws+WS_DGATES;
  for(int j=tid;j<3072;j+=256) x_lds[j]=x_dec[j];
  {
    const float* hp=h_dec+((t+1)&1)*1024;   // h_{t-1}
    for(int j=tid;j<1024;j+=256) x_lds[3072+j]=hp[j];
  }
  __syncthreads();
  const int wave=tid>>6, lane=tid&63;
  for(int rr=0;rr<2;rr++){
    int r=blockIdx.x*8+wave*2+rr;
    const float* wr=Wih_d+(size_t)r*3072;
    float acc=0.0f;
    #pragma unroll
    for(int c4=0;c4<12;c4++){
      int m=c4*256+lane*4;
      acc += d4(*(const float4*)(wr+m), *(const float4*)(&x_lds[m]));
    }
    const float* hr=Whh_d+(size_t)r*1024;
    #pragma unroll
    for(int c4=0;c4<4;c4++){
      int m=c4*256+lane*4;
      acc += d4(*(const float4*)(hr+m), *(const float4*)(&x_lds[3072+m]));
    }
    acc=wred_sum(acc);
    if(lane==0) dg[r]=acc+bih_d[r]+bhh_d[r];
  }
}

// ---------------- decoder gen: redundant cell update + gen/copy GEMV + softmax partials ----------------
__global__ __launch_bounds__(256) void k_dec_gen(
  const float* __restrict__ gen_W, const float* __restrict__ gen_b,
  const float* __restrict__ amask,
  float* __restrict__ ws, float* __restrict__ out, int t)
{
  __shared__ __align__(16) float h_lds[1024];
  __shared__ float w_lm[4], w_sm[4], w_ky[4];
  __shared__ int w_ix[4];
  const int tid=threadIdx.x;
  float* dg=ws+WS_DGATES;
  float* c_dec=ws+WS_C_DEC; float* h_dec=ws+WS_H_DEC;
  float* logits=ws+WS_LOGITS; float* parts=ws+WS_PARTS;
  float* cenc=ws+WS_COPY_ENC;
  {
    const float* cp=c_dec+((t+1)&1)*1024;   // c_{t-1}
    float* cw=c_dec+(t&1)*1024;
    float* hw=h_dec+(t&1)*1024;
    for(int u=tid;u<1024;u+=256){
      float ig=dg[u], fg=dg[1024+u], gg=dg[2048+u], og=dg[3072+u];
      float c=sigm(fg)*cp[u]+sigm(ig)*tanhf(gg);
      float h=sigm(og)*tanhf(c);
      h_lds[u]=h;
      if(blockIdx.x==0){ cw[u]=c; hw[u]=h; out[(size_t)(t+1)*1024+u]=h; }  // states[t+1]
    }
  }
  __syncthreads();
  const int wave=tid>>6, lane=tid&63;
  const int b=blockIdx.x;
  const bool isGen=(b<500);
  const int rbase = isGen ? (b*64+wave*16) : (VOCAB+wave*16);
  float lv[16];
  #pragma unroll
  for(int rr=0;rr<16;rr++){
    const float* wr = isGen ? gen_W+(size_t)(rbase+rr)*1024
                            : cenc +(size_t)(rbase-VOCAB+rr)*1024;
    float acc=0.0f;
    #pragma unroll
    for(int c4=0;c4<4;c4++){
      int m=c4*256+lane*4;
      acc += d4(*(const float4*)(wr+m), *(const float4*)(&h_lds[m]));
    }
    acc=wred_sum(acc);
    lv[rr] = isGen ? acc+gen_b[rbase+rr] : acc;
  }
  if(lane==0){
    float lm=-INFINITY, ky=-INFINITY; int ix=0;
    #pragma unroll
    for(int rr=0;rr<16;rr++){
      int gi=rbase+rr;
      logits[gi]=lv[rr];
      lm=fmaxf(lm,lv[rr]);
      float mk=amask[gi];
      float kk = (mk>0.0f)? (lv[rr]+__logf(mk)) : -INFINITY;
      if(kk>ky){ ky=kk; ix=gi; }   // strict > keeps first index on ties
    }
    float sm=0.0f;
    #pragma unroll
    for(int rr=0;rr<16;rr++) sm += __expf(lv[rr]-lm);
    w_lm[wave]=lm; w_sm[wave]=sm; w_ky[wave]=ky; w_ix[wave]=ix;
  }
  __syncthreads();
  if(tid==0){
    float lm=w_lm[0], sm=w_sm[0], ky=w_ky[0]; int ix=w_ix[0];
    for(int w=1;w<4;w++){
      float blm=w_lm[w], bsm=w_sm[w];
      if(blm>lm){ sm=sm*__expf(lm-blm)+bsm; lm=blm; }
      else sm += bsm*__expf(blm-lm);
      if(w_ky[w]>ky || (w_ky[w]==ky && w_ix[w]<ix)){ ky=w_ky[w]; ix=w_ix[w]; }
    }
    float4 p; p.x=lm; p.y=sm; p.z=ky; p.w=__int_as_float(ix);
    *(float4*)(parts+(size_t)blockIdx.x*4)=p;
  }
}

extern "C" void kernel_launch(void* const* d_in, const int* in_sizes, int n_in,
                              void* d_out, int out_size, void* d_ws, size_t ws_size,
                              hipStream_t stream)
{
  const int*   xt     = (const int*)d_in[0];
  const float* amask  = (const float*)d_in[1];
  const float* emb    = (const float*)d_in[2];
  const float* Wih_f  = (const float*)d_in[3];
  const float* Whh_f  = (const float*)d_in[4];
  const float* bih_f  = (const float*)d_in[5];
  const float* bhh_f  = (const float*)d_in[6];
  const float* Wih_b  = (const float*)d_in[7];
  const float* Whh_b  = (const float*)d_in[8];
  const float* bih_b  = (const float*)d_in[9];
  const float* bhh_b  = (const float*)d_in[10];
  const float* Wih_d  = (const float*)d_in[11];
  const float* Whh_d  = (const float*)d_in[12];
  const float* bih_d  = (const float*)d_in[13];
  const float* bhh_d  = (const float*)d_in[14];
  const float* attn_W = (const float*)d_in[15];
  const float* attn_b = (const float*)d_in[16];
  const float* gen_W  = (const float*)d_in[17];
  const float* gen_b  = (const float*)d_in[18];
  const float* copy_W = (const float*)d_in[19];
  const float* copy_b = (const float*)d_in[20];
  float* out=(float*)d_out;
  float* ws =(float*)d_ws;

  for(int t=0;t<L;t++)
    k_enc_step<<<512,256,0,stream>>>(xt,emb,Wih_f,Whh_f,bih_f,bhh_f,Wih_b,Whh_b,bih_b,bhh_b,ws,t);
  k_enc_final<<<1,256,0,stream>>>(ws,out);
  k_copy_enc<<<256,256,0,stream>>>(copy_W,copy_b,ws);

  k_dec_init<<<1,256,0,stream>>>(emb,ws);
  k_dec_gates<<<512,256,0,stream>>>(Wih_d,Whh_d,bih_d,bhh_d,ws,0);
  k_dec_gen  <<<501,256,0,stream>>>(gen_W,gen_b,amask,ws,out,0);
  for(int t=1;t<ML;t++){
    k_attn     <<<64,256,0,stream>>>(xt,amask,emb,attn_W,attn_b,ws,out,t,0);
    k_prep     <<<4,256,0,stream>>>(ws);
    k_dec_gates<<<512,256,0,stream>>>(Wih_d,Whh_d,bih_d,bhh_d,ws,t);
    k_dec_gen  <<<501,256,0,stream>>>(gen_W,gen_b,amask,ws,out,t);
  }
  k_attn<<<1,256,0,stream>>>(xt,amask,emb,attn_W,attn_b,ws,out,ML,1);
}